// Round 6
// baseline (280.514 us; speedup 1.0000x reference)
//
#include <hip/hip_runtime.h>

#define TOK 65536
#define DM 256
#define DF 1024
#define NB 4

typedef unsigned short ushort_t;
typedef unsigned int uint32;

typedef __attribute__((ext_vector_type(8))) short bf16x8;
typedef __attribute__((ext_vector_type(4))) float f32x4;
typedef __attribute__((ext_vector_type(4))) uint32 u32x4;

__device__ inline ushort_t f2bf(float f) {
  union { float f; unsigned int u; } v; v.f = f;
  unsigned int u = v.u;
  unsigned int r = (u + 0x7FFFu + ((u >> 16) & 1u)) >> 16;
  return (ushort_t)r;
}
__device__ inline float bf2f(ushort_t u) {
  union { unsigned int u; float f; } v; v.u = ((uint32)u) << 16; return v.f;
}
__device__ inline uint32 pack2(float a, float b) {
  return (uint32)f2bf(a) | ((uint32)f2bf(b) << 16);
}

// lgkm-only barrier: vmem loads stay in flight across it.
__device__ __forceinline__ void lbar() {
  __builtin_amdgcn_sched_barrier(0);
  __builtin_amdgcn_s_waitcnt(0xC07F);   // lgkmcnt(0), vmcnt untouched
  __builtin_amdgcn_s_barrier();
  __builtin_amdgcn_sched_barrier(0);
}

// ------- kernel 0: merged route + weight->fragment-layout conversion -------
// blocks [0,256): route 256 tokens each (counts pre-zeroed via hipMemsetAsync)
// blocks [256,768): W1 -> W1f frag layout; [768,1280): W2 -> W2f.
// Frag layouts (16B per frag-lane, 1KB per wave-frag, fully coalesced reads
// in the FFN kernel):
//  W1f[((n*32+fc)*2+fi)*8+ks][lane(q,lc)][j] = W1[n][fc*32+fi*16+lc][ks*32+q*8+j]
//  W2f[((n*32+fc)*4+dq)*4+di][lane(q,lc)][j] = W2[n][dq*64+di*16+lc][fc*32+q*8+j]
__global__ __launch_bounds__(256) void prep_route_kernel(
    const float* __restrict__ w1, const float* __restrict__ w2,
    ushort_t* __restrict__ w1fb, ushort_t* __restrict__ w2fb,
    const int* __restrict__ b_seq, int* __restrict__ counts,
    ushort_t* __restrict__ lists, u32x4* __restrict__ out16)
{
  const int bx = blockIdx.x;
  const int tid = threadIdx.x;
  if (bx >= 256) {
    const bool isw2 = bx >= 768;
    const int gid = (bx - (isw2 ? 768 : 256)) * 256 + tid;   // 0..131071
    const int lane_ = gid & 63;
    const int lcq = lane_ & 15, qq = lane_ >> 4;
    size_t src_off;
    if (!isw2) {
      int ks = (gid >> 6) & 7, fi = (gid >> 9) & 1;
      int fc = (gid >> 10) & 31, nn = gid >> 15;
      src_off = (size_t)(nn * 1024 + fc * 32 + fi * 16 + lcq) * 256 + ks * 32 + qq * 8;
    } else {
      int di = (gid >> 6) & 3, dqv = (gid >> 8) & 3;
      int fc = (gid >> 10) & 31, nn = gid >> 15;
      src_off = (size_t)(nn * 256 + dqv * 64 + di * 16 + lcq) * 1024 + fc * 32 + qq * 8;
    }
    const float* src = (isw2 ? w2 : w1) + src_off;
    f32x4 a = *(const f32x4*)src;
    f32x4 c = *(const f32x4*)(src + 4);
    u32x4 p;
    p.x = pack2(a.x, a.y); p.y = pack2(a.z, a.w);
    p.z = pack2(c.x, c.y); p.w = pack2(c.z, c.w);
    ushort_t* dst = isw2 ? w2fb : w1fb;
    *(u32x4*)(dst + (size_t)gid * 8) = p;    // off16 = frag*512+lane*8 = gid*8
    return;
  }
  // ---- route branch
  __shared__ int s_lpos[NB];
  __shared__ int s_lbase[NB];
  __shared__ int s_b[256];
  const int base = bx * 256;
  const int token = base + tid;
  if (tid < NB) s_lpos[tid] = 0;
  __syncthreads();
  const int b = b_seq[token];
  s_b[tid] = b;
  int my = 0;
  if (b > 0) my = atomicAdd(&s_lpos[b - 1], 1);
  __syncthreads();
  if (tid < NB) s_lbase[tid] = atomicAdd(&counts[tid], s_lpos[tid]);
  __syncthreads();
  if (b > 0) lists[(b - 1) * TOK + s_lbase[b - 1] + my] = (ushort_t)token;
  const u32x4 z = (u32x4){0u, 0u, 0u, 0u};
  #pragma unroll 4
  for (int it = 0; it < 64; ++it) {
    int flat = it * 256 + tid;
    int tl = flat >> 6;
    int j = flat & 63;
    if (s_b[tl] == 0) out16[(size_t)(base + tl) * 64 + j] = z;
  }
}

// ---------------- kernel 1: FFN + LN, weights direct-from-L2 ---------------
// Round-5 lesson: LDS pipe (one per CU) carried ~65% of cycles; every b128
// weight read (12 cyc) fed one MFMA (4.85 cyc over 4 SIMDs). Weights are
// L2-resident (1 MB/branch, XCD-affine) -> load B-fragments DIRECTLY from
// global in frag layout (coalesced 1KB/wave dwordx4), zero LDS for weights.
// Block = 4 waves, M=32 tokens, 32 chunks of F=32:
//  GEMM1 wave (fi=wv&1, mh=wv>>1): 16 tok x 16 f; xfrag[8]=32 VGPR.
//  GEMM2 wave (dq=wv): 32 tok x 64 d; yacc[2][4]=32 AGPR; W2 frags
//    register-double-buffered (w2A/w2B), loaded one chunk ahead.
// One lgkm-only barrier per chunk (sH handoff); vmem NEVER drained.
// LDS: sX 16K (transient) + sH 5K + stats ~ 25KB -> LDS allows 6 blocks;
// regs decide occupancy. All waves uniform (round-4 lesson).
__global__ __launch_bounds__(256, 3) void ffn_kernel(
    const float* __restrict__ x,
    const ushort_t* __restrict__ w1f_all, const float* __restrict__ b1,
    const ushort_t* __restrict__ w2f_all, const float* __restrict__ b2,
    const float* __restrict__ gamma, const float* __restrict__ beta,
    const int* __restrict__ counts, const ushort_t* __restrict__ lists,
    float* __restrict__ out)
{
  const int id = blockIdx.x;
  const int slot = id & 7;            // XCD affinity: branch n -> XCDs {2n,2n+1}
  const int n = slot >> 1;
  const int tile = ((id >> 3) << 1) + (slot & 1);
  const int cnt = counts[n];
  const int tile0 = tile * 32;
  if (tile0 >= cnt) return;           // block-uniform exit before any barrier
  const int mvalid = min(32, cnt - tile0);

  __shared__ __align__(16) ushort_t sX[32][256];      // 16 KB, XOR-swizzled
  __shared__ __align__(16) ushort_t sH[2][32][40];    // 5 KB double-buffer
  __shared__ ushort_t sB1[DF];
  __shared__ int s_idx[32];
  __shared__ float s_ps[4][32];
  __shared__ float s_pq[4][32];
  __shared__ float s_mu[32];
  __shared__ float s_rs[32];

  const int tid  = threadIdx.x;
  const int wv   = tid >> 6;          // 0..3
  const int lane = tid & 63;
  const int q    = lane >> 4;
  const int lc   = lane & 15;
  const int fi   = wv & 1;            // GEMM1 f-sub
  const int mh   = wv >> 1;           // GEMM1 token half (16 rows)
  const int dq   = wv;                // GEMM2 d-quarter (64 cols)

  const ushort_t* w1f = w1f_all + (size_t)n * 262144;   // 512 KB / branch
  const ushort_t* w2f = w2f_all + (size_t)n * 262144;

  if (tid < 32) {
    int i = tile0 + tid;
    s_idx[tid] = (int)lists[n * TOK + (i < cnt ? i : tile0)];
  }
  {
    f32x4 v = *(const f32x4*)(b1 + n * DF + tid * 4);
    uint2 p;
    p.x = pack2(v.x, v.y);
    p.y = pack2(v.z, v.w);
    *(uint2*)(sB1 + tid * 4) = p;
  }
  __syncthreads();                    // s_idx ready

  // ---- stage X tile 32x256 fp32 -> bf16 into sX, 16B-granule XOR swizzle
  #pragma unroll
  for (int it = 0; it < 4; ++it) {
    int flat = it * 256 + tid;
    int r = flat >> 5;                 // 0..31
    int c8 = flat & 31;
    const float* xp = x + (size_t)s_idx[r] * DM + c8 * 8;
    f32x4 a = *(const f32x4*)xp;
    f32x4 c = *(const f32x4*)(xp + 4);
    u32x4 p;
    p.x = pack2(a.x, a.y); p.y = pack2(a.z, a.w);
    p.z = pack2(c.x, c.y); p.w = pack2(c.z, c.w);
    *(u32x4*)(&sX[r][(c8 ^ r) * 8]) = p;
  }
  __syncthreads();                    // sX ready (never overwritten after)

  // ---- X A-frags: this wave's 16 tokens x K=256 (32 VGPR)
  bf16x8 xfrag[8];
  #pragma unroll
  for (int ks = 0; ks < 8; ++ks) {
    int row = mh * 16 + lc;
    int g = (ks * 4 + q) ^ row;
    xfrag[ks] = *(const bf16x8*)(&sX[row][g * 8]);
  }

  f32x4 yacc[2][4];                   // 32 tok x 64 d (32 AGPR)
  #pragma unroll
  for (int mi2 = 0; mi2 < 2; ++mi2)
    #pragma unroll
    for (int di = 0; di < 4; ++di)
      yacc[mi2][di] = (f32x4){0.f, 0.f, 0.f, 0.f};

  bf16x8 w2A[4], w2B[4];

  auto g2_load = [&](int fc, bf16x8 (&w2r)[4]) {
    const ushort_t* p = w2f + (size_t)(fc * 4 + dq) * 2048 + lane * 8;
    #pragma unroll
    for (int di = 0; di < 4; ++di)
      w2r[di] = *(const bf16x8*)(p + di * 512);
  };
  auto g2_comp = [&](int fc, bf16x8 (&w2r)[4]) {
    const int rb = fc & 1;
    bf16x8 af0 = *(const bf16x8*)(&sH[rb][lc][q * 8]);
    bf16x8 af1 = *(const bf16x8*)(&sH[rb][16 + lc][q * 8]);
    __builtin_amdgcn_s_setprio(1);
    #pragma unroll
    for (int di = 0; di < 4; ++di) {
      yacc[0][di] = __builtin_amdgcn_mfma_f32_16x16x32_bf16(af0, w2r[di], yacc[0][di], 0, 0, 0);
      yacc[1][di] = __builtin_amdgcn_mfma_f32_16x16x32_bf16(af1, w2r[di], yacc[1][di], 0, 0, 0);
    }
    __builtin_amdgcn_s_setprio(0);
  };
  auto g1 = [&](int fc) {
    const ushort_t* p = w1f + (size_t)(fc * 2 + fi) * 4096 + lane * 8;
    const float b1v = bf2f(sB1[fc * 32 + fi * 16 + lc]);
    f32x4 ha = (f32x4){0.f, 0.f, 0.f, 0.f};
    f32x4 hb = (f32x4){0.f, 0.f, 0.f, 0.f};
    __builtin_amdgcn_s_setprio(1);
    #pragma unroll
    for (int k2 = 0; k2 < 4; ++k2) {
      bf16x8 ba = *(const bf16x8*)(p + (2 * k2) * 512);
      bf16x8 bb = *(const bf16x8*)(p + (2 * k2 + 1) * 512);
      ha = __builtin_amdgcn_mfma_f32_16x16x32_bf16(xfrag[2 * k2],     ba, ha, 0, 0, 0);
      hb = __builtin_amdgcn_mfma_f32_16x16x32_bf16(xfrag[2 * k2 + 1], bb, hb, 0, 0, 0);
    }
    __builtin_amdgcn_s_setprio(0);
    #pragma unroll
    for (int r4 = 0; r4 < 4; ++r4) {
      float v = ha[r4] + hb[r4] + b1v;
      v = (v > 0.f) ? v : (__expf(v) - 1.f);
      sH[fc & 1][mh * 16 + q * 4 + r4][fi * 16 + lc] = f2bf(v);
    }
  };

  // Pipeline: GEMM2 one chunk behind GEMM1; W2 frags loaded one chunk ahead
  // into alternating register buffers (2-unrolled loop renames, no copies).
  g2_load(0, w2A);
  g1(0);
  #pragma unroll 1
  for (int i = 1; i < 32; i += 2) {
    lbar();
    g2_load(i, w2B);
    g2_comp(i - 1, w2A);
    g1(i);
    lbar();
    if (i + 1 < 32) g2_load(i + 1, w2A);
    g2_comp(i, w2B);
    if (i + 1 < 32) g1(i + 1);
  }

  // ================= epilogue: +b2, LN stats, gamma/beta, store ============
  float b2v[4], gv[4], bv[4];
  #pragma unroll
  for (int di = 0; di < 4; ++di) {
    int dcol = n * DM + dq * 64 + di * 16 + lc;
    b2v[di] = b2[dcol];
    gv[di]  = gamma[dcol];
    bv[di]  = beta[dcol];
  }
  #pragma unroll
  for (int mi2 = 0; mi2 < 2; ++mi2)
    #pragma unroll
    for (int di = 0; di < 4; ++di)
      #pragma unroll
      for (int r4 = 0; r4 < 4; ++r4)
        yacc[mi2][di][r4] += b2v[di];

  #pragma unroll
  for (int mi2 = 0; mi2 < 2; ++mi2) {
    #pragma unroll
    for (int r4 = 0; r4 < 4; ++r4) {
      float s = 0.f, sq = 0.f;
      #pragma unroll
      for (int di = 0; di < 4; ++di) {
        float v = yacc[mi2][di][r4];
        s += v; sq += v * v;
      }
      #pragma unroll
      for (int off = 1; off < 16; off <<= 1) {
        s  += __shfl_xor(s, off, 64);
        sq += __shfl_xor(sq, off, 64);
      }
      if (lc == 0) {
        int tok = mi2 * 16 + q * 4 + r4;
        s_ps[dq][tok] = s;
        s_pq[dq][tok] = sq;
      }
    }
  }
  __syncthreads();
  if (tid < 32) {
    float s  = s_ps[0][tid] + s_ps[1][tid] + s_ps[2][tid] + s_ps[3][tid];
    float sq = s_pq[0][tid] + s_pq[1][tid] + s_pq[2][tid] + s_pq[3][tid];
    float mu = s * (1.f / 256.f);
    float var = fmaxf(sq * (1.f / 256.f) - mu * mu, 0.f);
    s_mu[tid] = mu;
    s_rs[tid] = rsqrtf(var + 1e-12f);
  }
  __syncthreads();

  #pragma unroll
  for (int mi2 = 0; mi2 < 2; ++mi2) {
    #pragma unroll
    for (int r4 = 0; r4 < 4; ++r4) {
      int tok = mi2 * 16 + q * 4 + r4;
      if (tok < mvalid) {
        float mu = s_mu[tok], rs = s_rs[tok];
        size_t rowbase = (size_t)s_idx[tok] * DM + dq * 64;
        #pragma unroll
        for (int di = 0; di < 4; ++di) {
          float v = (yacc[mi2][di][r4] - mu) * rs * gv[di] + bv[di];
          out[rowbase + di * 16 + lc] = v;
        }
      }
    }
  }
}

extern "C" void kernel_launch(void* const* d_in, const int* in_sizes, int n_in,
                              void* d_out, int out_size, void* d_ws, size_t ws_size,
                              hipStream_t stream) {
  const float* x     = (const float*)d_in[0];
  const int*   b_seq = (const int*)d_in[1];
  const float* w1    = (const float*)d_in[2];
  const float* b1    = (const float*)d_in[3];
  const float* w2    = (const float*)d_in[4];
  const float* b2    = (const float*)d_in[5];
  const float* gamma = (const float*)d_in[6];
  const float* beta  = (const float*)d_in[7];
  float* out = (float*)d_out;

  int* counts = (int*)d_ws;
  ushort_t* lists = (ushort_t*)((char*)d_ws + 256);                 // 512 KB
  ushort_t* w1fb = (ushort_t*)((char*)d_ws + 256 + 512 * 1024);     // 2 MB
  ushort_t* w2fb = w1fb + (size_t)NB * DF * DM;                     // 2 MB

  hipMemsetAsync(counts, 0, 256, stream);
  // blocks [0,256): route; [256,768): W1f; [768,1280): W2f
  hipLaunchKernelGGL(prep_route_kernel, dim3(1280), dim3(256), 0, stream,
                     w1, w2, w1fb, w2fb, b_seq, counts, lists, (u32x4*)d_out);
  // 2048 tiles/branch capacity (32-token tiles): covers any imbalance
  hipLaunchKernelGGL(ffn_kernel, dim3(8192), dim3(256), 0, stream,
                     x, w1fb, b1, w2fb, b2, gamma, beta, counts, lists, out);
}